// Round 7
// baseline (143.752 us; speedup 1.0000x reference)
//
#include <hip/hip_runtime.h>
#include <math.h>

#define NN 16384
#define T 512

typedef float f2 __attribute__((ext_vector_type(2)));

// gfx950 VOP3P packed-FP32: only fma/add/mul/mov exist (no pk_min/pk_max).
// acc += x * {w,w}; w uniform -> SGPR pair (64-bit aligned operand).
__device__ __forceinline__ void pkfma(f2& acc, f2 x, float w) {
    f2 ws = {w, w};
    asm("v_pk_fma_f32 %0, %1, %2, %0"
        : "+v"(acc) : "v"(x), "s"(ws));
}

// scalar ELU applied to both halves (v_exp/v_max/v_min are scalar-only for f32)
__device__ __forceinline__ f2 elu2(f2 v) {
    f2 r;
    r.x = fmaxf(v.x, 0.0f) + fminf(__expf(v.x) - 1.0f, 0.0f);
    r.y = fmaxf(v.y, 0.0f) + fminf(__expf(v.y) - 1.0f, 0.0f);
    return r;
}

__global__ __launch_bounds__(256, 5)
void smag_pk(const float* __restrict__ x,
             const float* __restrict__ dw,
             const float* __restrict__ fw,
             const float* __restrict__ W1, const float* __restrict__ b1,
             const float* __restrict__ W2, const float* __restrict__ b2,
             const float* __restrict__ W3, const float* __restrict__ b3,
             float* __restrict__ out)
{
    const int blk = blockIdx.x & 31;        // 32 tiles per row
    const int row = blockIdx.x >> 5;
    const int tb  = blk * T;
    const int tid = threadIdx.x;
    const float* __restrict__ xr = x   + (size_t)row * NN;
    float* __restrict__ outr     = out + (size_t)row * NN;

    // One arena, even offsets -> every float2 access is 8B-aligned.
    __shared__ __align__(16) float sm[6812];
    float* const sx  = sm;          // [536]     x    : idx = p + 12, p in [-10,522)
    float* const sxd = sm + 536;    // [528]     xd   : idx = p + 8,  p in [-8,520)
    float* const sf1 = sm + 1064;   // [528]     f1   : idx = p + 8
    float* const sh1 = sm + 1592;   // [6][524]  h1   : idx = c*524 + p + 6, p in [-6,518)
    float* const sh2 = sm + 4736;   // [3][520]  h2   : idx = c*520 + p + 4, p in [-4,516)
    float* const sy  = sm + 6296;   // [516]     y    : idx = p + 2,  p in [-2,514)

    // ---- stage x into LDS (coalesced f2 + tiny circular halo) ----
    {
        f2 v = *(const f2*)(xr + tb + 2 * tid);
        *(f2*)(sx + 2 * tid + 12) = v;
        if (tid < 20) {
            int p = (tid < 10) ? (tid - 10) : (T + tid - 10);
            sx[p + 12] = xr[(tb + p + NN) & (NN - 1)];
        }
    }

    const float d0 = dw[0], d1 = dw[1], d2 = dw[2], d3 = dw[3], d4 = dw[4];
    const float g0 = fw[0], g1 = fw[1], g2 = fw[2];
    const f2 zero = {0.0f, 0.0f};
    __syncthreads();

    // ---- stage 1: xdiff + (x - box) on pairs, p in [-8,520) ----
    auto S1 = [&](int p) {
        f2 L0 = *(f2*)(sx + p + 10);     // x[p-2], x[p-1]
        f2 L1 = *(f2*)(sx + p + 12);     // x[p],   x[p+1]
        f2 L2 = *(f2*)(sx + p + 14);     // x[p+2], x[p+3]
        f2 a12 = {L0.y, L1.x};
        f2 a34 = {L1.y, L2.x};
        f2 xd = zero;
        pkfma(xd, L0, d0); pkfma(xd, a12, d1); pkfma(xd, L1, d2);
        pkfma(xd, a34, d3); pkfma(xd, L2, d4);
        f2 bx = zero;
        pkfma(bx, a12, g0); pkfma(bx, L1, g1); pkfma(bx, a34, g2);
        f2 f1v = L1;
        pkfma(f1v, bx, -1.0f);           // f1 = L1 - bx
        *(f2*)(sxd + p + 8) = xd;
        *(f2*)(sf1 + p + 8) = f1v;
    };
    S1(2 * tid - 8);
    if (tid < 8) S1(504 + 2 * tid);
    __syncthreads();

    // ---- stage 2: h1 = elu(conv5(feat,W1)+b1), p in [-6,518) ----
    auto S2 = [&](int p) {
        f2 X0 = *(f2*)(sxd + p + 6);
        f2 X1 = *(f2*)(sxd + p + 8);
        f2 X2 = *(f2*)(sxd + p + 10);
        f2 F0 = *(f2*)(sf1 + p + 6);
        f2 F1 = *(f2*)(sf1 + p + 8);
        f2 F2 = *(f2*)(sf1 + p + 10);
        f2 xa[5] = {X0, {X0.y, X1.x}, X1, {X1.y, X2.x}, X2};
        f2 fa[5] = {F0, {F0.y, F1.x}, F1, {F1.y, F2.x}, F2};
        #pragma unroll
        for (int c = 0; c < 6; ++c) {
            f2 a = {b1[c], b1[c]};
            #pragma unroll
            for (int k = 0; k < 5; ++k) {
                pkfma(a, xa[k], W1[c * 10 + k]);
                pkfma(a, fa[k], W1[c * 10 + 5 + k]);
            }
            *(f2*)(sh1 + c * 524 + p + 6) = elu2(a);
        }
    };
    S2(2 * tid - 6);
    if (tid < 6) S2(506 + 2 * tid);
    __syncthreads();

    // ---- stage 3: h2 = elu(conv5(h1,W2)+b2), p in [-4,516) ----
    auto S3 = [&](int p) {
        f2 acc0 = {b2[0], b2[0]};
        f2 acc1 = {b2[1], b2[1]};
        f2 acc2 = {b2[2], b2[2]};
        #pragma unroll
        for (int ci = 0; ci < 6; ++ci) {
            const float* hb = sh1 + ci * 524 + p + 4;   // h1[ci] at position p-2
            f2 H0 = *(f2*)(hb);
            f2 H1 = *(f2*)(hb + 2);
            f2 H2 = *(f2*)(hb + 4);
            f2 ha[5] = {H0, {H0.y, H1.x}, H1, {H1.y, H2.x}, H2};
            #pragma unroll
            for (int k = 0; k < 5; ++k) {
                pkfma(acc0, ha[k], W2[0 * 30 + ci * 5 + k]);
                pkfma(acc1, ha[k], W2[1 * 30 + ci * 5 + k]);
                pkfma(acc2, ha[k], W2[2 * 30 + ci * 5 + k]);
            }
        }
        *(f2*)(sh2 + 0 * 520 + p + 4) = elu2(acc0);
        *(f2*)(sh2 + 1 * 520 + p + 4) = elu2(acc1);
        *(f2*)(sh2 + 2 * 520 + p + 4) = elu2(acc2);
    };
    S3(2 * tid - 4);
    if (tid < 4) S3(508 + 2 * tid);
    __syncthreads();

    // ---- stage 4: cs -> y (sqrt2 folded), p in [-2,514) ----
    const float B3v = b3[0];
    auto S4 = [&](int p) {
        f2 a = {B3v, B3v};
        #pragma unroll
        for (int ci = 0; ci < 3; ++ci) {
            const float* hb = sh2 + ci * 520 + p + 2;   // h2[ci] at position p-2
            f2 H0 = *(f2*)(hb);
            f2 H1 = *(f2*)(hb + 2);
            f2 H2 = *(f2*)(hb + 4);
            f2 ha1 = {H0.y, H1.x};
            f2 ha3 = {H1.y, H2.x};
            pkfma(a, H0, W3[ci * 5 + 0]); pkfma(a, ha1, W3[ci * 5 + 1]);
            pkfma(a, H1, W3[ci * 5 + 2]); pkfma(a, ha3, W3[ci * 5 + 3]);
            pkfma(a, H2, W3[ci * 5 + 4]);
        }
        f2 cs = elu2(a);
        f2 xd = *(f2*)(sxd + p + 8);
        const float CUT = (float)(2.0 / 16384.0);
        const float SQ2 = 1.41421356237309515f;
        f2 y;
        {
            float c0 = fminf(fmaxf(cs.x, 0.0f), 1.0f);
            float t0 = c0 * CUT;
            y.x = SQ2 * t0 * t0 * fabsf(xd.x) * xd.x;
            float c1 = fminf(fmaxf(cs.y, 0.0f), 1.0f);
            float t1 = c1 * CUT;
            y.y = SQ2 * t1 * t1 * fabsf(xd.y) * xd.y;
        }
        *(f2*)(sy + p + 2) = y;
    };
    S4(2 * tid - 2);
    if (tid < 2) S4(510 + 2 * tid);
    __syncthreads();

    // ---- stage 5: out = conv5(y, dw), straight to global (coalesced f2) ----
    {
        const int p = 2 * tid;
        f2 Y0 = *(f2*)(sy + p);          // y[p-2], y[p-1]
        f2 Y1 = *(f2*)(sy + p + 2);      // y[p],   y[p+1]
        f2 Y2 = *(f2*)(sy + p + 4);      // y[p+2], y[p+3]
        f2 a12 = {Y0.y, Y1.x};
        f2 a34 = {Y1.y, Y2.x};
        f2 o = zero;
        pkfma(o, Y0, d0); pkfma(o, a12, d1); pkfma(o, Y1, d2);
        pkfma(o, a34, d3); pkfma(o, Y2, d4);
        *(f2*)(outr + tb + p) = o;
    }
}

extern "C" void kernel_launch(void* const* d_in, const int* in_sizes, int n_in,
                              void* d_out, int out_size, void* d_ws, size_t ws_size,
                              hipStream_t stream) {
    const float* x  = (const float*)d_in[0];
    const float* dw = (const float*)d_in[1];
    const float* fw = (const float*)d_in[2];
    const float* W1 = (const float*)d_in[3];
    const float* b1 = (const float*)d_in[4];
    const float* W2 = (const float*)d_in[5];
    const float* b2 = (const float*)d_in[6];
    const float* W3 = (const float*)d_in[7];
    const float* b3 = (const float*)d_in[8];
    float* out = (float*)d_out;

    const int B = 1024;
    dim3 grid(B * (NN / T));    // 32768 blocks
    dim3 block(256);
    hipLaunchKernelGGL(smag_pk, grid, block, 0, stream,
                       x, dw, fw, W1, b1, W2, b2, W3, b3, out);
}

// Round 8
// 132.592 us; speedup vs baseline: 1.0842x; 1.0842x over previous
//
#include <hip/hip_runtime.h>
#include <math.h>

#define NN 16384
#define T 512

typedef float f2 __attribute__((ext_vector_type(2)));

// gfx950 VOP3P packed-FP32 fma; w uniform -> SGPR pair source.
// Used ONLY for even taps where sources are naturally even-aligned pairs.
__device__ __forceinline__ void pkfma(f2& acc, f2 x, float w) {
    f2 ws = {w, w};
    asm("v_pk_fma_f32 %0, %1, %2, %0"
        : "+v"(acc) : "v"(x), "s"(ws));
}

// scalar ELU halves (no packed f32 min/max/exp on gfx950)
__device__ __forceinline__ f2 elu2(f2 v) {
    f2 r;
    r.x = fmaxf(v.x, 0.0f) + fminf(__expf(v.x) - 1.0f, 0.0f);
    r.y = fmaxf(v.y, 0.0f) + fminf(__expf(v.y) - 1.0f, 0.0f);
    return r;
}

__global__ __launch_bounds__(256, 5)
void smag_hy(const float* __restrict__ x,
             const float* __restrict__ dw,
             const float* __restrict__ fw,
             const float* __restrict__ W1, const float* __restrict__ b1,
             const float* __restrict__ W2, const float* __restrict__ b2,
             const float* __restrict__ W3, const float* __restrict__ b3,
             float* __restrict__ out)
{
    const int blk = blockIdx.x & 31;        // 32 tiles per row
    const int row = blockIdx.x >> 5;
    const int tb  = blk * T;
    const int tid = threadIdx.x;
    const float* __restrict__ xr = x   + (size_t)row * NN;
    float* __restrict__ outr     = out + (size_t)row * NN;

    // One arena, even offsets -> every float2 access is 8B-aligned.
    __shared__ __align__(16) float sm[6812];
    float* const sx  = sm;          // [536]     x    : idx = p + 12, p in [-10,522)
    float* const sxd = sm + 536;    // [528]     xd   : idx = p + 8,  p in [-8,520)
    float* const sf1 = sm + 1064;   // [528]     f1   : idx = p + 8
    float* const sh1 = sm + 1592;   // [6][524]  h1   : idx = c*524 + p + 6, p in [-6,518)
    float* const sh2 = sm + 4736;   // [3][520]  h2   : idx = c*520 + p + 4, p in [-4,516)
    float* const sy  = sm + 6296;   // [516]     y    : idx = p + 2,  p in [-2,514)

    // ---- stage x into LDS (coalesced f2 + tiny circular halo) ----
    {
        f2 v = *(const f2*)(xr + tb + 2 * tid);
        *(f2*)(sx + 2 * tid + 12) = v;
        if (tid < 20) {
            int p = (tid < 10) ? (tid - 10) : (T + tid - 10);
            sx[p + 12] = xr[(tb + p + NN) & (NN - 1)];
        }
    }

    const float d0 = dw[0], d1 = dw[1], d2 = dw[2], d3 = dw[3], d4 = dw[4];
    const float g0 = fw[0], g1 = fw[1], g2 = fw[2];
    __syncthreads();

    // ---- stage 1: xdiff + (x - box) on pairs, p in [-8,520) ----
    auto S1 = [&](int p) {
        f2 L0 = *(f2*)(sx + p + 10);     // x[p-2], x[p-1]
        f2 L1 = *(f2*)(sx + p + 12);     // x[p],   x[p+1]
        f2 L2 = *(f2*)(sx + p + 14);     // x[p+2], x[p+3]
        // odd taps scalar, even taps packed
        f2 xd = { fmaf(d1, L0.y, d3 * L1.y), fmaf(d1, L1.x, d3 * L2.x) };
        pkfma(xd, L0, d0); pkfma(xd, L1, d2); pkfma(xd, L2, d4);
        f2 bx = { fmaf(g0, L0.y, g2 * L1.y), fmaf(g0, L1.x, g2 * L2.x) };
        pkfma(bx, L1, g1);
        f2 f1v = { L1.x - bx.x, L1.y - bx.y };
        *(f2*)(sxd + p + 8) = xd;
        *(f2*)(sf1 + p + 8) = f1v;
    };
    S1(2 * tid - 8);
    if (tid < 8) S1(504 + 2 * tid);
    __syncthreads();

    // ---- stage 2: h1 = elu(conv5(feat,W1)+b1), p in [-6,518) ----
    auto S2 = [&](int p) {
        f2 X0 = *(f2*)(sxd + p + 6);
        f2 X1 = *(f2*)(sxd + p + 8);
        f2 X2 = *(f2*)(sxd + p + 10);
        f2 F0 = *(f2*)(sf1 + p + 6);
        f2 F1 = *(f2*)(sf1 + p + 8);
        f2 F2 = *(f2*)(sf1 + p + 10);
        #pragma unroll
        for (int c = 0; c < 6; ++c) {
            const float w1x = W1[c*10 + 1], w3x = W1[c*10 + 3];
            const float w1f = W1[c*10 + 6], w3f = W1[c*10 + 8];
            const float bb  = b1[c];
            f2 a;
            a.x = fmaf(w1x, X0.y, fmaf(w3x, X1.y, fmaf(w1f, F0.y, fmaf(w3f, F1.y, bb))));
            a.y = fmaf(w1x, X1.x, fmaf(w3x, X2.x, fmaf(w1f, F1.x, fmaf(w3f, F2.x, bb))));
            pkfma(a, X0, W1[c*10 + 0]); pkfma(a, X1, W1[c*10 + 2]); pkfma(a, X2, W1[c*10 + 4]);
            pkfma(a, F0, W1[c*10 + 5]); pkfma(a, F1, W1[c*10 + 7]); pkfma(a, F2, W1[c*10 + 9]);
            *(f2*)(sh1 + c * 524 + p + 6) = elu2(a);
        }
    };
    S2(2 * tid - 6);
    if (tid < 6) S2(506 + 2 * tid);
    __syncthreads();

    // ---- stage 3: h2 = elu(conv5(h1,W2)+b2), p in [-4,516) ----
    auto S3 = [&](int p) {
        f2 acc0 = {b2[0], b2[0]};
        f2 acc1 = {b2[1], b2[1]};
        f2 acc2 = {b2[2], b2[2]};
        #pragma unroll
        for (int ci = 0; ci < 6; ++ci) {
            const float* hb = sh1 + ci * 524 + p + 4;   // h1[ci] at position p-2
            f2 H0 = *(f2*)(hb);
            f2 H1 = *(f2*)(hb + 2);
            f2 H2 = *(f2*)(hb + 4);
            #pragma unroll
            for (int o = 0; o < 3; ++o) {
                f2& acc = (o == 0) ? acc0 : (o == 1) ? acc1 : acc2;
                const float w0 = W2[o*30 + ci*5 + 0];
                const float w1 = W2[o*30 + ci*5 + 1];
                const float w2 = W2[o*30 + ci*5 + 2];
                const float w3 = W2[o*30 + ci*5 + 3];
                const float w4 = W2[o*30 + ci*5 + 4];
                acc.x = fmaf(w1, H0.y, fmaf(w3, H1.y, acc.x));
                acc.y = fmaf(w1, H1.x, fmaf(w3, H2.x, acc.y));
                pkfma(acc, H0, w0); pkfma(acc, H1, w2); pkfma(acc, H2, w4);
            }
        }
        *(f2*)(sh2 + 0 * 520 + p + 4) = elu2(acc0);
        *(f2*)(sh2 + 1 * 520 + p + 4) = elu2(acc1);
        *(f2*)(sh2 + 2 * 520 + p + 4) = elu2(acc2);
    };
    S3(2 * tid - 4);
    if (tid < 4) S3(508 + 2 * tid);
    __syncthreads();

    // ---- stage 4: cs -> y, p in [-2,514) ----
    // clip(elu(a),0,1) == clamp(a,0,1) exactly (a<=0 -> elu in (-1,0] -> 0).
    const float B3v = b3[0];
    const float K = 1.41421356237309515f * (float)(2.0/16384.0) * (float)(2.0/16384.0);
    auto S4 = [&](int p) {
        f2 a = {B3v, B3v};
        #pragma unroll
        for (int ci = 0; ci < 3; ++ci) {
            const float* hb = sh2 + ci * 520 + p + 2;   // h2[ci] at position p-2
            f2 H0 = *(f2*)(hb);
            f2 H1 = *(f2*)(hb + 2);
            f2 H2 = *(f2*)(hb + 4);
            const float w0 = W3[ci*5 + 0], w1 = W3[ci*5 + 1], w2 = W3[ci*5 + 2];
            const float w3 = W3[ci*5 + 3], w4 = W3[ci*5 + 4];
            a.x = fmaf(w1, H0.y, fmaf(w3, H1.y, a.x));
            a.y = fmaf(w1, H1.x, fmaf(w3, H2.x, a.y));
            pkfma(a, H0, w0); pkfma(a, H1, w2); pkfma(a, H2, w4);
        }
        f2 xd = *(f2*)(sxd + p + 8);
        f2 y;
        {
            float c0 = fminf(fmaxf(a.x, 0.0f), 1.0f);
            y.x = (c0 * c0 * K) * fabsf(xd.x) * xd.x;
            float c1 = fminf(fmaxf(a.y, 0.0f), 1.0f);
            y.y = (c1 * c1 * K) * fabsf(xd.y) * xd.y;
        }
        *(f2*)(sy + p + 2) = y;
    };
    S4(2 * tid - 2);
    if (tid < 2) S4(510 + 2 * tid);
    __syncthreads();

    // ---- stage 5: out = conv5(y, dw), straight to global (coalesced f2) ----
    {
        const int p = 2 * tid;
        f2 Y0 = *(f2*)(sy + p);          // y[p-2], y[p-1]
        f2 Y1 = *(f2*)(sy + p + 2);      // y[p],   y[p+1]
        f2 Y2 = *(f2*)(sy + p + 4);      // y[p+2], y[p+3]
        f2 o = { fmaf(d1, Y0.y, d3 * Y1.y), fmaf(d1, Y1.x, d3 * Y2.x) };
        pkfma(o, Y0, d0); pkfma(o, Y1, d2); pkfma(o, Y2, d4);
        *(f2*)(outr + tb + p) = o;
    }
}

extern "C" void kernel_launch(void* const* d_in, const int* in_sizes, int n_in,
                              void* d_out, int out_size, void* d_ws, size_t ws_size,
                              hipStream_t stream) {
    const float* x  = (const float*)d_in[0];
    const float* dw = (const float*)d_in[1];
    const float* fw = (const float*)d_in[2];
    const float* W1 = (const float*)d_in[3];
    const float* b1 = (const float*)d_in[4];
    const float* W2 = (const float*)d_in[5];
    const float* b2 = (const float*)d_in[6];
    const float* W3 = (const float*)d_in[7];
    const float* b3 = (const float*)d_in[8];
    float* out = (float*)d_out;

    const int B = 1024;
    dim3 grid(B * (NN / T));    // 32768 blocks
    dim3 block(256);
    hipLaunchKernelGGL(smag_hy, grid, block, 0, stream,
                       x, dw, fw, W1, b1, W2, b2, W3, b3, out);
}

// Round 9
// 116.215 us; speedup vs baseline: 1.2369x; 1.1409x over previous
//
#include <hip/hip_runtime.h>
#include <math.h>

#define NN 16384
#define T 512

typedef float f2 __attribute__((ext_vector_type(2)));

__device__ __forceinline__ f2 elu2(f2 v) {
    f2 e;
    e.x = __expf(v.x);
    e.y = __expf(v.y);
    const f2 zero = (f2)0.0f;
    return __builtin_elementwise_max(v, zero)
         + __builtin_elementwise_min(e - 1.0f, zero);
}

__global__ __launch_bounds__(256, 8)
void smag_al(const float* __restrict__ x,
             const float* __restrict__ dw,
             const float* __restrict__ fw,
             const float* __restrict__ W1, const float* __restrict__ b1,
             const float* __restrict__ W2, const float* __restrict__ b2,
             const float* __restrict__ W3, const float* __restrict__ b3,
             float* __restrict__ out)
{
    const int blk = blockIdx.x & 31;        // 32 tiles per row
    const int row = blockIdx.x >> 5;
    const int tb  = blk * T;
    const int tid = threadIdx.x;
    const float* __restrict__ xr = x   + (size_t)row * NN;
    float* __restrict__ outr     = out + (size_t)row * NN;

    // Aliased LDS arena (5232 floats = 20.9 KB -> 7 blocks/CU).
    // Lifetimes (all overlaps separated by barriers):
    //   sxd [0,528)      live S1..S4
    //   sh1 [528,3672)   live S2..S3    | sy [528,1044)  live S4..S5 (sh1 dead)
    //   sh2 [3672,5232)  live S3..S4    | sx [3672,4208) live load..S1 (pre-S3)
    //                                   | sf1[4208,4736) live S1..S2  (pre-S3)
    __shared__ __align__(16) float sm[5232];
    float* const sxd = sm;          // xd : idx = p + 8,  p in [-8,520)
    float* const sh1 = sm + 528;    // [6][524] h1 : idx = c*524 + p + 6, p in [-6,518)
    float* const sy  = sm + 528;    // y  : idx = p + 2,  p in [-2,514)
    float* const sh2 = sm + 3672;   // [3][520] h2 : idx = c*520 + p + 4, p in [-4,516)
    float* const sx  = sm + 3672;   // x  : idx = p + 12, p in [-10,522)
    float* const sf1 = sm + 4208;   // f1 : idx = p + 8,  p in [-8,520)

    // ---- stage x into LDS (coalesced f2 + tiny circular halo) ----
    {
        f2 v = *(const f2*)(xr + tb + 2 * tid);
        *(f2*)(sx + 2 * tid + 12) = v;
        if (tid < 20) {
            int p = (tid < 10) ? (tid - 10) : (T + tid - 10);
            sx[p + 12] = xr[(tb + p + NN) & (NN - 1)];
        }
    }

    const float d0 = dw[0], d1 = dw[1], d2 = dw[2], d3 = dw[3], d4 = dw[4];
    const float g0 = fw[0], g1 = fw[1], g2 = fw[2];
    __syncthreads();

    // ---- stage 1: xdiff + (x - box) on pairs, p in [-8,520) ----
    auto S1 = [&](int p) {
        f2 L0 = *(f2*)(sx + p + 10);     // x[p-2], x[p-1]
        f2 L1 = *(f2*)(sx + p + 12);     // x[p],   x[p+1]
        f2 L2 = *(f2*)(sx + p + 14);     // x[p+2], x[p+3]
        f2 a12 = {L0.y, L1.x};
        f2 a34 = {L1.y, L2.x};
        f2 xd = L0 * d0 + a12 * d1 + L1 * d2 + a34 * d3 + L2 * d4;
        f2 f1 = L1 - (a12 * g0 + L1 * g1 + a34 * g2);
        *(f2*)(sxd + p + 8) = xd;
        *(f2*)(sf1 + p + 8) = f1;
    };
    S1(2 * tid - 8);
    if (tid < 8) S1(504 + 2 * tid);
    __syncthreads();

    // ---- stage 2: h1 = elu(conv5(feat,W1)+b1), p in [-6,518) ----
    auto S2 = [&](int p) {
        f2 X0 = *(f2*)(sxd + p + 6);
        f2 X1 = *(f2*)(sxd + p + 8);
        f2 X2 = *(f2*)(sxd + p + 10);
        f2 F0 = *(f2*)(sf1 + p + 6);
        f2 F1 = *(f2*)(sf1 + p + 8);
        f2 F2 = *(f2*)(sf1 + p + 10);
        f2 xa[5] = {X0, {X0.y, X1.x}, X1, {X1.y, X2.x}, X2};
        f2 fa[5] = {F0, {F0.y, F1.x}, F1, {F1.y, F2.x}, F2};
        #pragma unroll
        for (int c = 0; c < 6; ++c) {
            f2 a = (f2)b1[c];
            #pragma unroll
            for (int k = 0; k < 5; ++k)
                a = a + xa[k] * W1[c * 10 + k] + fa[k] * W1[c * 10 + 5 + k];
            *(f2*)(sh1 + c * 524 + p + 6) = elu2(a);
        }
    };
    S2(2 * tid - 6);
    if (tid < 6) S2(506 + 2 * tid);
    __syncthreads();

    // ---- stage 3: h2 = elu(conv5(h1,W2)+b2), p in [-4,516) ----
    auto S3 = [&](int p) {
        f2 acc0 = (f2)b2[0], acc1 = (f2)b2[1], acc2 = (f2)b2[2];
        #pragma unroll
        for (int ci = 0; ci < 6; ++ci) {
            const float* hb = sh1 + ci * 524 + p + 4;   // h1[ci] at position p-2
            f2 H0 = *(f2*)(hb);
            f2 H1 = *(f2*)(hb + 2);
            f2 H2 = *(f2*)(hb + 4);
            f2 ha[5] = {H0, {H0.y, H1.x}, H1, {H1.y, H2.x}, H2};
            #pragma unroll
            for (int k = 0; k < 5; ++k) {
                acc0 = acc0 + ha[k] * W2[0 * 30 + ci * 5 + k];
                acc1 = acc1 + ha[k] * W2[1 * 30 + ci * 5 + k];
                acc2 = acc2 + ha[k] * W2[2 * 30 + ci * 5 + k];
            }
        }
        *(f2*)(sh2 + 0 * 520 + p + 4) = elu2(acc0);
        *(f2*)(sh2 + 1 * 520 + p + 4) = elu2(acc1);
        *(f2*)(sh2 + 2 * 520 + p + 4) = elu2(acc2);
    };
    S3(2 * tid - 4);
    if (tid < 4) S3(508 + 2 * tid);
    __syncthreads();

    // ---- stage 4: cs -> y, p in [-2,514) ----
    // clip(elu(a),0,1) == clamp(a,0,1) exactly; K = sqrt2 * CUTOFF^2.
    const float B3v = b3[0];
    const float K = 1.41421356237309515f * (float)(2.0/16384.0) * (float)(2.0/16384.0);
    auto S4 = [&](int p) {
        f2 a = (f2)B3v;
        #pragma unroll
        for (int ci = 0; ci < 3; ++ci) {
            const float* hb = sh2 + ci * 520 + p + 2;   // h2[ci] at position p-2
            f2 H0 = *(f2*)(hb);
            f2 H1 = *(f2*)(hb + 2);
            f2 H2 = *(f2*)(hb + 4);
            f2 ha1 = {H0.y, H1.x};
            f2 ha3 = {H1.y, H2.x};
            a = a + H0 * W3[ci * 5 + 0] + ha1 * W3[ci * 5 + 1] + H1 * W3[ci * 5 + 2]
                  + ha3 * W3[ci * 5 + 3] + H2 * W3[ci * 5 + 4];
        }
        f2 xd = *(f2*)(sxd + p + 8);
        f2 cs = __builtin_elementwise_min(__builtin_elementwise_max(a, (f2)0.0f), (f2)1.0f);
        f2 axd = __builtin_elementwise_abs(xd);
        f2 y = (cs * cs) * (axd * xd) * K;
        *(f2*)(sy + p + 2) = y;
    };
    S4(2 * tid - 2);
    if (tid < 2) S4(510 + 2 * tid);
    __syncthreads();

    // ---- stage 5: out = conv5(y, dw), straight to global (coalesced f2) ----
    {
        const int p = 2 * tid;
        f2 Y0 = *(f2*)(sy + p);          // y[p-2], y[p-1]
        f2 Y1 = *(f2*)(sy + p + 2);      // y[p],   y[p+1]
        f2 Y2 = *(f2*)(sy + p + 4);      // y[p+2], y[p+3]
        f2 a12 = {Y0.y, Y1.x};
        f2 a34 = {Y1.y, Y2.x};
        f2 o = Y0 * d0 + a12 * d1 + Y1 * d2 + a34 * d3 + Y2 * d4;
        *(f2*)(outr + tb + p) = o;
    }
}

extern "C" void kernel_launch(void* const* d_in, const int* in_sizes, int n_in,
                              void* d_out, int out_size, void* d_ws, size_t ws_size,
                              hipStream_t stream) {
    const float* x  = (const float*)d_in[0];
    const float* dw = (const float*)d_in[1];
    const float* fw = (const float*)d_in[2];
    const float* W1 = (const float*)d_in[3];
    const float* b1 = (const float*)d_in[4];
    const float* W2 = (const float*)d_in[5];
    const float* b2 = (const float*)d_in[6];
    const float* W3 = (const float*)d_in[7];
    const float* b3 = (const float*)d_in[8];
    float* out = (float*)d_out;

    const int B = 1024;
    dim3 grid(B * (NN / T));    // 32768 blocks
    dim3 block(256);
    hipLaunchKernelGGL(smag_al, grid, block, 0, stream,
                       x, dw, fw, W1, b1, W2, b2, W3, b3, out);
}

// Round 10
// 111.543 us; speedup vs baseline: 1.2888x; 1.0419x over previous
//
#include <hip/hip_runtime.h>
#include <math.h>

#define NN 16384
#define T 512

typedef float f2 __attribute__((ext_vector_type(2)));

__device__ __forceinline__ f2 elu2(f2 v) {
    f2 e;
    e.x = __expf(v.x);
    e.y = __expf(v.y);
    const f2 zero = (f2)0.0f;
    return __builtin_elementwise_max(v, zero)
         + __builtin_elementwise_min(e - 1.0f, zero);
}

// ---- setup: composite 9-tap weights cw[6][9] = conv1 ∘ [deriv ; I - box] ----
__global__ void smag_setup(const float* __restrict__ dw,
                           const float* __restrict__ fw,
                           const float* __restrict__ W1,
                           float* __restrict__ cw)
{
    const int t = threadIdx.x;
    if (t < 54) {
        const int c = t / 9;
        const int m = (t % 9) - 4;                 // tap offset in [-4,4]
        float acc = 0.0f;
        // xdiff path: sum_k W1[c,0,k] * D[m+4-k]
        #pragma unroll
        for (int k = 0; k < 5; ++k) {
            int j = m + 4 - k;
            if (j >= 0 && j <= 4) acc += W1[c * 10 + k] * dw[j];
        }
        // identity part of (x - box): W1[c,1,m+2]
        if (m >= -2 && m <= 2) acc += W1[c * 10 + 5 + (m + 2)];
        // -box part: -sum_i F[i] * W1[c,1,m+3-i]
        #pragma unroll
        for (int i = 0; i < 3; ++i) {
            int k = m + 3 - i;
            if (k >= 0 && k <= 4) acc -= fw[i] * W1[c * 10 + 5 + k];
        }
        cw[t] = acc;
    }
}

__global__ __launch_bounds__(256, 8)
void smag_c9(const float* __restrict__ x,
             const float* __restrict__ dw,
             const float* __restrict__ cw,    // [6][9] composite
             const float* __restrict__ b1,
             const float* __restrict__ W2, const float* __restrict__ b2,
             const float* __restrict__ W3, const float* __restrict__ b3,
             float* __restrict__ out)
{
    const int blk = blockIdx.x & 31;        // 32 tiles per row
    const int row = blockIdx.x >> 5;
    const int tb  = blk * T;
    const int tid = threadIdx.x;
    const float* __restrict__ xr = x   + (size_t)row * NN;
    float* __restrict__ outr     = out + (size_t)row * NN;

    // Aliased arena: 4704 floats = 18.8 KB -> 8 blocks/CU (32-wave cap).
    //   sh1 [0,3144)    live S2..S3   | sy [0,516) live S4..S5 (sh1 dead)
    //   sh2 [3144,4704) live S3..S4
    __shared__ __align__(16) float sm[4704];
    float* const sh1 = sm;          // [6][524] h1 : idx = c*524 + p + 6, p in [-6,518)
    float* const sy  = sm;          // y  : idx = p + 2, p in [-2,514)
    float* const sh2 = sm + 3144;   // [3][520] h2 : idx = c*520 + p + 4, p in [-4,516)

    const float d0 = dw[0], d1 = dw[1], d2 = dw[2], d3 = dw[3], d4 = dw[4];

    // ---- stage 2': h1 = elu(conv9(x, cw) + b1) at pair p; also xd at p+4 ----
    f2 xd_main, xd_tail;
    auto S2p = [&](int p, f2& xd_out) {
        // G[t] = x pair at position p-4+2t (circular, even offsets never straddle wrap)
        f2 G[6];
        #pragma unroll
        for (int t = 0; t < 6; ++t) {
            int g = (tb + p - 4 + 2 * t + NN) & (NN - 1);
            G[t] = *(const f2*)(xr + g);
        }
        // 9 windows: even taps aligned, odd taps cross-pair
        f2 w9[9] = {G[0], {G[0].y, G[1].x}, G[1], {G[1].y, G[2].x}, G[2],
                    {G[2].y, G[3].x}, G[3], {G[3].y, G[4].x}, G[4]};
        #pragma unroll
        for (int c = 0; c < 6; ++c) {
            f2 a = (f2)b1[c];
            #pragma unroll
            for (int m = 0; m < 9; ++m)
                a = a + w9[m] * cw[c * 9 + m];
            *(f2*)(sh1 + c * 524 + p + 6) = elu2(a);
        }
        // xd at position p+4 (this thread's S4 anchor): window x[p+2 .. p+7]
        f2 a12 = {G[3].y, G[4].x};
        f2 a34 = {G[4].y, G[5].x};
        xd_out = G[3] * d0 + a12 * d1 + G[4] * d2 + a34 * d3 + G[5] * d4;
    };
    S2p(2 * tid - 6, xd_main);
    if (tid < 6) S2p(506 + 2 * tid, xd_tail);
    __syncthreads();

    // ---- stage 3: h2 = elu(conv5(h1,W2)+b2), q in [-4,516) ----
    auto S3 = [&](int q) {
        f2 acc0 = (f2)b2[0], acc1 = (f2)b2[1], acc2 = (f2)b2[2];
        #pragma unroll
        for (int ci = 0; ci < 6; ++ci) {
            const float* hb = sh1 + ci * 524 + q + 4;   // h1[ci] at q-2
            f2 H0 = *(f2*)(hb);
            f2 H1 = *(f2*)(hb + 2);
            f2 H2 = *(f2*)(hb + 4);
            f2 ha[5] = {H0, {H0.y, H1.x}, H1, {H1.y, H2.x}, H2};
            #pragma unroll
            for (int k = 0; k < 5; ++k) {
                acc0 = acc0 + ha[k] * W2[0 * 30 + ci * 5 + k];
                acc1 = acc1 + ha[k] * W2[1 * 30 + ci * 5 + k];
                acc2 = acc2 + ha[k] * W2[2 * 30 + ci * 5 + k];
            }
        }
        *(f2*)(sh2 + 0 * 520 + q + 4) = elu2(acc0);
        *(f2*)(sh2 + 1 * 520 + q + 4) = elu2(acc1);
        *(f2*)(sh2 + 2 * 520 + q + 4) = elu2(acc2);
    };
    S3(2 * tid - 4);
    if (tid < 4) S3(508 + 2 * tid);
    __syncthreads();

    // ---- stage 4: cs -> y, q in [-2,514); clip(elu(a),0,1) == clamp(a,0,1) ----
    const float B3v = b3[0];
    const float K = 1.41421356237309515f * (float)(2.0/16384.0) * (float)(2.0/16384.0);
    auto S4 = [&](int q, f2 xd) {
        f2 a = (f2)B3v;
        #pragma unroll
        for (int ci = 0; ci < 3; ++ci) {
            const float* hb = sh2 + ci * 520 + q + 2;   // h2[ci] at q-2
            f2 H0 = *(f2*)(hb);
            f2 H1 = *(f2*)(hb + 2);
            f2 H2 = *(f2*)(hb + 4);
            f2 ha1 = {H0.y, H1.x};
            f2 ha3 = {H1.y, H2.x};
            a = a + H0 * W3[ci * 5 + 0] + ha1 * W3[ci * 5 + 1] + H1 * W3[ci * 5 + 2]
                  + ha3 * W3[ci * 5 + 3] + H2 * W3[ci * 5 + 4];
        }
        f2 cs = __builtin_elementwise_min(__builtin_elementwise_max(a, (f2)0.0f), (f2)1.0f);
        f2 axd = __builtin_elementwise_abs(xd);
        f2 y = (cs * cs) * (axd * xd) * K;
        *(f2*)(sy + q + 2) = y;
    };
    S4(2 * tid - 2, xd_main);
    if (tid < 2) S4(510 + 2 * tid, xd_tail);
    __syncthreads();

    // ---- stage 5: out = conv5(y, dw), coalesced f2 store ----
    {
        const int p = 2 * tid;
        f2 Y0 = *(f2*)(sy + p);          // y[p-2], y[p-1]
        f2 Y1 = *(f2*)(sy + p + 2);      // y[p],   y[p+1]
        f2 Y2 = *(f2*)(sy + p + 4);      // y[p+2], y[p+3]
        f2 a12 = {Y0.y, Y1.x};
        f2 a34 = {Y1.y, Y2.x};
        f2 o = Y0 * d0 + a12 * d1 + Y1 * d2 + a34 * d3 + Y2 * d4;
        *(f2*)(outr + tb + p) = o;
    }
}

extern "C" void kernel_launch(void* const* d_in, const int* in_sizes, int n_in,
                              void* d_out, int out_size, void* d_ws, size_t ws_size,
                              hipStream_t stream) {
    const float* x  = (const float*)d_in[0];
    const float* dw = (const float*)d_in[1];
    const float* fw = (const float*)d_in[2];
    const float* W1 = (const float*)d_in[3];
    const float* b1 = (const float*)d_in[4];
    const float* W2 = (const float*)d_in[5];
    const float* b2 = (const float*)d_in[6];
    const float* W3 = (const float*)d_in[7];
    const float* b3 = (const float*)d_in[8];
    float* out = (float*)d_out;
    float* cw  = (float*)d_ws;   // 54 floats

    hipLaunchKernelGGL(smag_setup, dim3(1), dim3(64), 0, stream, dw, fw, W1, cw);

    const int B = 1024;
    dim3 grid(B * (NN / T));    // 32768 blocks
    dim3 block(256);
    hipLaunchKernelGGL(smag_c9, grid, block, 0, stream,
                       x, dw, cw, b1, W2, b2, W3, b3, out);
}